// Round 7
// baseline (219.249 us; speedup 1.0000x reference)
//
#include <hip/hip_runtime.h>
#include <stdint.h>

// triplet_loss_cl: loss = mean_i(-log(softmax(q G^T)[i,i] + 1e-5)), N=8192, D=256.
// Flash-style, never materialize logits. q pre-scaled by log2(e); MFMA C-input
// initialized to -KOFF so logits exit MFMA already offset; epilogue is bare exp2.
// Offset cancels exactly in p = exp2(l_ii)/sum exp2(l).
//
// Round 7: MX-scaled fp8 K=128 (mfma_scale_f32_16x16x128_f8f6f4, scales=1.0)
// -> 2x MFMA rate vs r6; LDS double-buffer with post-barrier prefetch so the
// vmcnt(0)-before-s_barrier drain only waits on loads issued a full compute
// phase earlier. A/B share one chunk map: any k-permutation in the HW fragment
// layout hits both operands and cancels in the dot. C/D layout is
// shape-determined (col=lane&15, row=quad*4+reg) -> diag extraction unchanged.

#define LOG2E 1.44269504f
#define KOFF  92.3324826f          // 64 * log2(e); cancels exactly in p = e_ii/Z
#define SCL1  0x7F7F7F7F           // E8M0 127 = 2^0 in every byte

typedef __attribute__((ext_vector_type(4))) float f32x4;
typedef __attribute__((ext_vector_type(8))) int   i32x8;

typedef __attribute__((address_space(1))) const uint32_t gu32;
typedef __attribute__((address_space(3))) uint32_t lu32;

// ---- kernel 0: fp32 row-major [8192][256] -> fp8 MX panel-fragment layout ----
// Panel = 64 rows (16 KB). Fragment chunk (h*4+cf) is 2 KB, split in two 1 KB
// halves: lane*16 holds k = h*128 + quad*32 + sub*16 .. +16 for row cf*16+l15
// (lane = quad*16+l15, sub = which half). q pre-scaled by log2(e).
__global__ __launch_bounds__(256) void k_cvt(const float* __restrict__ q,
                                             const float* __restrict__ g,
                                             char* __restrict__ qb,
                                             char* __restrict__ gb) {
    int o = blockIdx.x * 256 + threadIdx.x;        // grid 1024: q then g
    const float* src = q;
    char* dst = qb;
    float sc = LOG2E;
    if (o >= 131072) { o -= 131072; src = g; dst = gb; sc = 1.0f; }
    int row = o >> 4, seg = o & 15;                // seg: 16 floats = 16 k
    const float4* sp = (const float4*)(src + row * 256 + seg * 16);
    float4 f0 = sp[0], f1 = sp[1], f2 = sp[2], f3 = sp[3];
    uint32_t w0 = __builtin_amdgcn_cvt_pk_fp8_f32(f0.x * sc, f0.y * sc, 0, false);
    w0 = __builtin_amdgcn_cvt_pk_fp8_f32(f0.z * sc, f0.w * sc, w0, true);
    uint32_t w1 = __builtin_amdgcn_cvt_pk_fp8_f32(f1.x * sc, f1.y * sc, 0, false);
    w1 = __builtin_amdgcn_cvt_pk_fp8_f32(f1.z * sc, f1.w * sc, w1, true);
    uint32_t w2 = __builtin_amdgcn_cvt_pk_fp8_f32(f2.x * sc, f2.y * sc, 0, false);
    w2 = __builtin_amdgcn_cvt_pk_fp8_f32(f2.z * sc, f2.w * sc, w2, true);
    uint32_t w3 = __builtin_amdgcn_cvt_pk_fp8_f32(f3.x * sc, f3.y * sc, 0, false);
    w3 = __builtin_amdgcn_cvt_pk_fp8_f32(f3.z * sc, f3.w * sc, w3, true);
    int p = row >> 6, cf = (row >> 4) & 3, l15 = row & 15;
    int h = seg >> 3, sub = seg & 1, quad = (seg >> 1) & 3;
    int lane = quad * 16 + l15;
    uint4 wv; wv.x = w0; wv.y = w1; wv.z = w2; wv.w = w3;
    *(uint4*)(dst + (size_t)p * 16384 + (h * 4 + cf) * 2048 + sub * 1024 + lane * 16) = wv;
}

// ---- kernel 1: per-row Z partials (+ diagonal offset-logits) ----
// grid 1024 = 32 row-tiles (BM=256) x 32 col-splits (256 cols). 4 waves x 64 rows.
// Per jt (64-col tile): 16 KB DMA (double-buffered), 4cf x (2h x 4rg MFMA K=128).
__global__ __launch_bounds__(256, 2) void k_main(const char* __restrict__ qb,
                                                 const char* __restrict__ gb,
                                                 float* __restrict__ zpart,
                                                 float* __restrict__ diag) {
    __shared__ char lds[32768];                    // 2 x 16 KB double buffer
    const int tid  = threadIdx.x;
    const int wave = tid >> 6;
    const int lane = tid & 63;
    const int l15  = lane & 15;
    const int quad = lane >> 4;
    const int t    = blockIdx.x >> 5;              // row-tile (256 rows)
    const int cs   = blockIdx.x & 31;              // col-split (256 cols)
    const int rowbase = t * 256 + wave * 64;
    const char* gp0 = gb + (size_t)(cs * 4) * 16384;

    // DMA jt=0 into buffer 0 (4 waves x 4 x 1KB; dest = uniform + lane*16)
#pragma unroll
    for (int i = 0; i < 4; ++i) {
        int c = wave * 4 + i;
        __builtin_amdgcn_global_load_lds(
            (gu32*)(gp0 + (c << 10) + (lane << 4)),
            (lu32*)(lds + (c << 10)), 16, 0, 0);
    }

    // A fragments: wave owns q-panel (t*4+wave); rg x k-half, 8 regs each = 64 VGPRs.
    i32x8 afrag[4][2];
    {
        const char* qp = qb + (size_t)(t * 4 + wave) * 16384 + (lane << 4);
#pragma unroll
        for (int rg = 0; rg < 4; ++rg)
#pragma unroll
            for (int h = 0; h < 2; ++h) {
                union { uint4 u[2]; i32x8 v; } cv;
                cv.u[0] = *(const uint4*)(qp + ((h * 4 + rg) << 11));
                cv.u[1] = *(const uint4*)(qp + ((h * 4 + rg) << 11) + 1024);
                afrag[rg][h] = cv.v;
            }
    }

    float zacc[4][4];
#pragma unroll
    for (int rg = 0; rg < 4; ++rg)
#pragma unroll
        for (int r = 0; r < 4; ++r) zacc[rg][r] = 0.f;

    const bool bd = (t == cs);                     // square block on the diagonal

    for (int jt = 0; jt < 4; ++jt) {
        __syncthreads();                           // drains DMA issued a phase ago
        if (jt < 3) {                              // prefetch jt+1 into other buffer
            const char* gp = gp0 + ((jt + 1) << 14);
            char* lb = lds + (((jt + 1) & 1) << 14);
#pragma unroll
            for (int i = 0; i < 4; ++i) {
                int c = wave * 4 + i;
                __builtin_amdgcn_global_load_lds(
                    (gu32*)(gp + (c << 10) + (lane << 4)),
                    (lu32*)(lb + (c << 10)), 16, 0, 0);
            }
        }
        const char* lb = lds + ((jt & 1) << 14);
        const bool dg = bd && (jt == wave);        // this tile holds our diagonal
#pragma unroll
        for (int cf = 0; cf < 4; ++cf) {
            f32x4 acc[4];
#pragma unroll
            for (int rg = 0; rg < 4; ++rg)
                acc[rg] = (f32x4){-KOFF, -KOFF, -KOFF, -KOFF};
#pragma unroll
            for (int h = 0; h < 2; ++h) {
                union { uint4 u[2]; i32x8 v; } bv;
                bv.u[0] = *(const uint4*)(lb + ((h * 4 + cf) << 11) + (lane << 4));
                bv.u[1] = *(const uint4*)(lb + ((h * 4 + cf) << 11) + 1024 + (lane << 4));
#pragma unroll
                for (int rg = 0; rg < 4; ++rg)
                    acc[rg] = __builtin_amdgcn_mfma_scale_f32_16x16x128_f8f6f4(
                        afrag[rg][h], bv.v, acc[rg], 0, 0, 0, SCL1, 0, SCL1);
            }
            // C/D layout: col=lane&15, row=quad*4+reg (shape-determined, m121+)
#pragma unroll
            for (int rg = 0; rg < 4; ++rg)
#pragma unroll
                for (int r = 0; r < 4; ++r)
                    zacc[rg][r] += __builtin_amdgcn_exp2f(acc[rg][r]);
            if (dg) {                              // diag: rg==cf, col l15 == row quad*4+r
#pragma unroll
                for (int r = 0; r < 4; ++r)
                    if (quad * 4 + r == l15)
                        diag[rowbase + cf * 16 + l15] = acc[cf][r];
            }
        }
    }

    // fold the 16 column-lane-classes (lanes differing in bits 0..3 share a row)
#pragma unroll
    for (int d = 1; d < 16; d <<= 1)
#pragma unroll
        for (int rg = 0; rg < 4; ++rg)
#pragma unroll
            for (int r = 0; r < 4; ++r)
                zacc[rg][r] += __shfl_xor(zacc[rg][r], d, 64);

    if (l15 == 0) {
#pragma unroll
        for (int rg = 0; rg < 4; ++rg)
#pragma unroll
            for (int r = 0; r < 4; ++r)
                zpart[(rowbase + rg * 16 + quad * 4 + r) * 32 + cs] = zacc[rg][r];
    }
}

// ---- kernel 2a: per-row loss, 32-block tree ----
__global__ __launch_bounds__(256) void k_fin1(const float* __restrict__ zpart,
                                              const float* __restrict__ diag,
                                              float* __restrict__ partial) {
    __shared__ float red[4];
    int r = blockIdx.x * 256 + threadIdx.x;
    const float4* z = (const float4*)(zpart + r * 32);
    float Z = 0.f;
#pragma unroll
    for (int i = 0; i < 8; ++i) {
        float4 a = z[i];
        Z += (a.x + a.y) + (a.z + a.w);
    }
    float p = __builtin_amdgcn_exp2f(diag[r]) / Z;  // diag already has -KOFF folded
    float v = -logf(p + 1e-5f);
#pragma unroll
    for (int dd = 1; dd < 64; dd <<= 1) v += __shfl_xor(v, dd, 64);
    if ((threadIdx.x & 63) == 0) red[threadIdx.x >> 6] = v;
    __syncthreads();
    if (threadIdx.x == 0)
        partial[blockIdx.x] = (red[0] + red[1]) + (red[2] + red[3]);
}

// ---- kernel 2b: final reduce ----
__global__ void k_fin2(const float* __restrict__ partial, float* __restrict__ out) {
    float v = (threadIdx.x < 32) ? partial[threadIdx.x] : 0.f;
#pragma unroll
    for (int d = 1; d < 32; d <<= 1) v += __shfl_xor(v, d, 64);
    if (threadIdx.x == 0) out[0] = v * (1.f / 8192.f);
}

extern "C" void kernel_launch(void* const* d_in, const int* in_sizes, int n_in,
                              void* d_out, int out_size, void* d_ws, size_t ws_size,
                              hipStream_t stream) {
    const float* q = (const float*)d_in[0];
    const float* g = (const float*)d_in[1];
    char* ws = (char*)d_ws;
    char*  qb     = ws;                                        // 2 MiB fp8 panels
    char*  gb     = ws + (2u << 20);                           // 2 MiB fp8 panels
    float* diag   = (float*)(ws + (4u << 20));                 // 32 KiB
    float* zpart  = (float*)(ws + (4u << 20) + (32u << 10));   // 1 MiB
    float* partial= (float*)(ws + (4u << 20) + (1056u << 10)); // 128 B
    k_cvt <<<1024, 256, 0, stream>>>(q, g, qb, gb);
    k_main<<<1024, 256, 0, stream>>>(qb, gb, zpart, diag);
    k_fin1<<<32,   256, 0, stream>>>(zpart, diag, partial);
    k_fin2<<<1,     64, 0, stream>>>(partial, (float*)d_out);
    (void)in_sizes; (void)n_in; (void)out_size; (void)ws_size;
}

// Round 8
// 124.492 us; speedup vs baseline: 1.7611x; 1.7611x over previous
//
#include <hip/hip_runtime.h>
#include <stdint.h>

// triplet_loss_cl: loss = mean_i(-log(softmax(q G^T)[i,i] + 1e-5)), N=8192, D=256.
// Flash-style, never materialize logits. q pre-scaled by log2(e); MFMA C-input
// initialized to -KOFF so logits exit MFMA already offset; epilogue is bare exp2.
// Offset cancels exactly in p = exp2(l_ii)/sum exp2(l).
//
// Round 8: r6 (clean non-scaled fp8 e4m3, no spill) + LDS double-buffer with
// post-barrier prefetch: DMA for jt+1 issued right AFTER the barrier, so the
// compiler's vmcnt(0)-before-s_barrier drain waits on loads issued a full
// compute phase (~1500 cyc) earlier -> drain stall ~0; barriers 8 -> 4.
// MX-scaled path abandoned: 8-reg A/B tuples spill at this budget (r7: 311 MB
// scratch writes, MfmaUtil 4%).

#define LOG2E 1.44269504f
#define KOFF  92.3324826f          // 64 * log2(e); cancels exactly in p = e_ii/Z

typedef __attribute__((ext_vector_type(4))) float f32x4;
typedef long long i64;

typedef __attribute__((address_space(1))) const uint32_t gu32;
typedef __attribute__((address_space(3))) uint32_t lu32;

// ---- kernel 0: fp32 row-major [8192][256] -> fp8 e4m3 panel-fragment layout ----
// Panel = 64 rows (16 KB). Chunk s = ks*4+cf (512 B) holds rows cf*16+l15,
// k = ks*32 + quad*8 .. +8, at byte (quad*16+l15)*8. q pre-scaled by log2(e).
__global__ __launch_bounds__(256) void k_cvt(const float* __restrict__ q,
                                             const float* __restrict__ g,
                                             char* __restrict__ qb,
                                             char* __restrict__ gb) {
    int o = blockIdx.x * 256 + threadIdx.x;        // grid 2048: q then g
    const float* src = q;
    char* dst = qb;
    float sc = LOG2E;
    if (o >= 262144) { o -= 262144; src = g; dst = gb; sc = 1.0f; }
    int row = o >> 5, slot = o & 31;
    int ks = slot >> 2, quad = slot & 3;
    const float4* sp = (const float4*)(src + row * 256 + slot * 8);
    float4 a = sp[0], b = sp[1];
    uint32_t w0 = __builtin_amdgcn_cvt_pk_fp8_f32(a.x * sc, a.y * sc, 0, false);
    w0 = __builtin_amdgcn_cvt_pk_fp8_f32(a.z * sc, a.w * sc, w0, true);
    uint32_t w1 = __builtin_amdgcn_cvt_pk_fp8_f32(b.x * sc, b.y * sc, 0, false);
    w1 = __builtin_amdgcn_cvt_pk_fp8_f32(b.z * sc, b.w * sc, w1, true);
    int p = row >> 6, cf = (row >> 4) & 3, l15 = row & 15;
    uint2 wv; wv.x = w0; wv.y = w1;
    *(uint2*)(dst + (size_t)p * 16384 + (ks * 4 + cf) * 512 + (quad * 16 + l15) * 8) = wv;
}

// ---- kernel 1: per-row Z partials (+ diagonal offset-logits) ----
// grid 1024 = 32 row-tiles (BM=256) x 32 col-splits (256 cols). 4 waves x 64 rows.
// Per jt (64-col tile): compute on buf jt&1 while DMAing jt+1 into buf (jt+1)&1.
__global__ __launch_bounds__(256, 2) void k_main(const char* __restrict__ qb,
                                                 const char* __restrict__ gb,
                                                 float* __restrict__ zpart,
                                                 float* __restrict__ diag) {
    __shared__ char lds[32768];                    // 2 x 16 KB double buffer
    const int tid  = threadIdx.x;
    const int wave = tid >> 6;
    const int lane = tid & 63;
    const int l15  = lane & 15;
    const int quad = lane >> 4;
    const int t    = blockIdx.x >> 5;              // row-tile (256 rows)
    const int cs   = blockIdx.x & 31;              // col-split (256 cols)
    const int rowbase = t * 256 + wave * 64;
    const char* gp0 = gb + (size_t)(cs * 4) * 16384;

    // DMA jt=0 into buffer 0 (4 waves x 4 x 1KB; dest = uniform + lane*16)
#pragma unroll
    for (int i = 0; i < 4; ++i) {
        int c = wave * 4 + i;
        __builtin_amdgcn_global_load_lds(
            (gu32*)(gp0 + (c << 10) + (lane << 4)),
            (lu32*)(lds + (c << 10)), 16, 0, 0);
    }

    // A fragments: wave owns exactly q-panel (t*4+wave); rowgroup rg = chunk cf.
    i64 afrag[4][8];                               // 64 VGPRs
    {
        const char* qp = qb + (size_t)(t * 4 + wave) * 16384 + lane * 8;
#pragma unroll
        for (int rg = 0; rg < 4; ++rg)
#pragma unroll
            for (int ks = 0; ks < 8; ++ks)
                afrag[rg][ks] = *(const i64*)(qp + ((ks * 4 + rg) << 9));
    }

    float zacc[4][4];
#pragma unroll
    for (int rg = 0; rg < 4; ++rg)
#pragma unroll
        for (int r = 0; r < 4; ++r) zacc[rg][r] = 0.f;

    const bool bd = (t == cs);                     // square block on the diagonal

    for (int jt = 0; jt < 4; ++jt) {
        __syncthreads();                           // drains DMA issued a phase ago
        if (jt < 3) {                              // prefetch jt+1 into other buffer
            const char* gp = gp0 + ((jt + 1) << 14);
            char* lb = lds + (((jt + 1) & 1) << 14);
#pragma unroll
            for (int i = 0; i < 4; ++i) {
                int c = wave * 4 + i;
                __builtin_amdgcn_global_load_lds(
                    (gu32*)(gp + (c << 10) + (lane << 4)),
                    (lu32*)(lb + (c << 10)), 16, 0, 0);
            }
        }
        const char* lb = lds + ((jt & 1) << 14);
        const bool dg = bd && (jt == wave);        // this tile holds our diagonal
#pragma unroll
        for (int cf = 0; cf < 4; ++cf) {
            f32x4 acc[4];
#pragma unroll
            for (int rg = 0; rg < 4; ++rg)
                acc[rg] = (f32x4){-KOFF, -KOFF, -KOFF, -KOFF};
#pragma unroll
            for (int ks = 0; ks < 8; ++ks) {
                i64 b = *(const i64*)(lb + ((ks * 4 + cf) << 9) + lane * 8);
#pragma unroll
                for (int rg = 0; rg < 4; ++rg)
                    acc[rg] = __builtin_amdgcn_mfma_f32_16x16x32_fp8_fp8(
                        afrag[rg][ks], b, acc[rg], 0, 0, 0);
            }
            // C/D layout: col=lane&15, row=quad*4+reg (dtype-independent, m121+)
#pragma unroll
            for (int rg = 0; rg < 4; ++rg)
#pragma unroll
                for (int r = 0; r < 4; ++r)
                    zacc[rg][r] += __builtin_amdgcn_exp2f(acc[rg][r]);
            if (dg) {                              // diag: rg==cf, col l15 == row quad*4+r
#pragma unroll
                for (int r = 0; r < 4; ++r)
                    if (quad * 4 + r == l15)
                        diag[rowbase + cf * 16 + l15] = acc[cf][r];
            }
        }
    }

    // fold the 16 column-lane-classes (lanes differing in bits 0..3 share a row)
#pragma unroll
    for (int d = 1; d < 16; d <<= 1)
#pragma unroll
        for (int rg = 0; rg < 4; ++rg)
#pragma unroll
            for (int r = 0; r < 4; ++r)
                zacc[rg][r] += __shfl_xor(zacc[rg][r], d, 64);

    if (l15 == 0) {
#pragma unroll
        for (int rg = 0; rg < 4; ++rg)
#pragma unroll
            for (int r = 0; r < 4; ++r)
                zpart[(rowbase + rg * 16 + quad * 4 + r) * 32 + cs] = zacc[rg][r];
    }
}

// ---- kernel 2a: per-row loss, 32-block tree ----
__global__ __launch_bounds__(256) void k_fin1(const float* __restrict__ zpart,
                                              const float* __restrict__ diag,
                                              float* __restrict__ partial) {
    __shared__ float red[4];
    int r = blockIdx.x * 256 + threadIdx.x;
    const float4* z = (const float4*)(zpart + r * 32);
    float Z = 0.f;
#pragma unroll
    for (int i = 0; i < 8; ++i) {
        float4 a = z[i];
        Z += (a.x + a.y) + (a.z + a.w);
    }
    float p = __builtin_amdgcn_exp2f(diag[r]) / Z;  // diag already has -KOFF folded
    float v = -logf(p + 1e-5f);
#pragma unroll
    for (int dd = 1; dd < 64; dd <<= 1) v += __shfl_xor(v, dd, 64);
    if ((threadIdx.x & 63) == 0) red[threadIdx.x >> 6] = v;
    __syncthreads();
    if (threadIdx.x == 0)
        partial[blockIdx.x] = (red[0] + red[1]) + (red[2] + red[3]);
}

// ---- kernel 2b: final reduce ----
__global__ void k_fin2(const float* __restrict__ partial, float* __restrict__ out) {
    float v = (threadIdx.x < 32) ? partial[threadIdx.x] : 0.f;
#pragma unroll
    for (int d = 1; d < 32; d <<= 1) v += __shfl_xor(v, d, 64);
    if (threadIdx.x == 0) out[0] = v * (1.f / 8192.f);
}

extern "C" void kernel_launch(void* const* d_in, const int* in_sizes, int n_in,
                              void* d_out, int out_size, void* d_ws, size_t ws_size,
                              hipStream_t stream) {
    const float* q = (const float*)d_in[0];
    const float* g = (const float*)d_in[1];
    char* ws = (char*)d_ws;
    char*  qb     = ws;                                        // 2 MiB fp8 panels
    char*  gb     = ws + (2u << 20);                           // 2 MiB fp8 panels
    float* diag   = (float*)(ws + (4u << 20));                 // 32 KiB
    float* zpart  = (float*)(ws + (4u << 20) + (32u << 10));   // 1 MiB
    float* partial= (float*)(ws + (4u << 20) + (1056u << 10)); // 128 B
    k_cvt <<<2048, 256, 0, stream>>>(q, g, qb, gb);
    k_main<<<1024, 256, 0, stream>>>(qb, gb, zpart, diag);
    k_fin1<<<32,   256, 0, stream>>>(zpart, diag, partial);
    k_fin2<<<1,     64, 0, stream>>>(partial, (float*)d_out);
    (void)in_sizes; (void)n_in; (void)out_size; (void)ws_size;
}

// Round 9
// 102.867 us; speedup vs baseline: 2.1314x; 1.2102x over previous
//
#include <hip/hip_runtime.h>
#include <stdint.h>

// triplet_loss_cl: loss = mean_i(-log(softmax(q G^T)[i,i] + 1e-5)), N=8192, D=256.
// Flash-style, never materialize logits. q pre-scaled by log2(e); MFMA C-input
// initialized to -KOFF so logits exit MFMA already offset; epilogue is bare exp2.
// Offset cancels exactly in p = exp2(l_ii)/sum exp2(l).
//
// Round 9: spill-proof footprint. 32 rows/wave fp8 (afrag[2][8]=32 VGPRs, the
// r1-class ~90-reg budget that never spilled), BM=128, cs=32 -> grid 2048 =
// 8 blocks/CU (barrier drains overlap across blocks). Single 16 KB LDS buffer,
// r6 barrier pattern. Spill history: every 64-row/wave variant (r4/r5/r7/r8)
// spilled (114-311 MB scratch writes); this is the structural fix.

#define LOG2E 1.44269504f
#define KOFF  92.3324826f          // 64 * log2(e); cancels exactly in p = e_ii/Z

typedef __attribute__((ext_vector_type(4))) float f32x4;
typedef long long i64;

typedef __attribute__((address_space(1))) const uint32_t gu32;
typedef __attribute__((address_space(3))) uint32_t lu32;

// ---- kernel 0: fp32 row-major [8192][256] -> fp8 e4m3 panel-fragment layout ----
// Panel = 64 rows (16 KB). Chunk s = ks*4+cf (512 B) holds rows cf*16+l15,
// k = ks*32 + quad*8 .. +8, at byte (quad*16+l15)*8. q pre-scaled by log2(e).
__global__ __launch_bounds__(256) void k_cvt(const float* __restrict__ q,
                                             const float* __restrict__ g,
                                             char* __restrict__ qb,
                                             char* __restrict__ gb) {
    int o = blockIdx.x * 256 + threadIdx.x;        // grid 2048: q then g
    const float* src = q;
    char* dst = qb;
    float sc = LOG2E;
    if (o >= 262144) { o -= 262144; src = g; dst = gb; sc = 1.0f; }
    int row = o >> 5, slot = o & 31;
    int ks = slot >> 2, quad = slot & 3;
    const float4* sp = (const float4*)(src + row * 256 + slot * 8);
    float4 a = sp[0], b = sp[1];
    uint32_t w0 = __builtin_amdgcn_cvt_pk_fp8_f32(a.x * sc, a.y * sc, 0, false);
    w0 = __builtin_amdgcn_cvt_pk_fp8_f32(a.z * sc, a.w * sc, w0, true);
    uint32_t w1 = __builtin_amdgcn_cvt_pk_fp8_f32(b.x * sc, b.y * sc, 0, false);
    w1 = __builtin_amdgcn_cvt_pk_fp8_f32(b.z * sc, b.w * sc, w1, true);
    int p = row >> 6, cf = (row >> 4) & 3, l15 = row & 15;
    uint2 wv; wv.x = w0; wv.y = w1;
    *(uint2*)(dst + (size_t)p * 16384 + (ks * 4 + cf) * 512 + (quad * 16 + l15) * 8) = wv;
}

// ---- kernel 1: per-row Z partials (+ diagonal offset-logits) ----
// grid 2048 = 64 row-tiles (BM=128) x 32 col-splits (256 cols). 4 waves x 32 rows.
// Per jt (64-col tile): DMA 16 KB, sync, 4cf x (8ks x 2rg MFMA), sync.
__global__ __launch_bounds__(256, 2) void k_main(const char* __restrict__ qb,
                                                 const char* __restrict__ gb,
                                                 float* __restrict__ zpart,
                                                 float* __restrict__ diag) {
    __shared__ char lds[16384];                    // one 64-col fp8 B tile
    const int tid  = threadIdx.x;
    const int wave = tid >> 6;
    const int lane = tid & 63;
    const int l15  = lane & 15;
    const int quad = lane >> 4;
    const int t    = blockIdx.x >> 5;              // row-tile (128 rows)
    const int cs   = blockIdx.x & 31;              // col-split (256 cols)
    const int rowbase = t * 128 + wave * 32;
    const char* gp0 = gb + (size_t)(cs * 4) * 16384;

    // A fragments: panel t*2+(wave>>1), rows (wave&1)*32 + rg*16 + l15.
    i64 afrag[2][8];                               // 32 VGPRs
    {
        const char* qp = qb + (size_t)(t * 2 + (wave >> 1)) * 16384 + lane * 8;
        const int cfa = (wave & 1) * 2;
#pragma unroll
        for (int rg = 0; rg < 2; ++rg)
#pragma unroll
            for (int ks = 0; ks < 8; ++ks)
                afrag[rg][ks] = *(const i64*)(qp + ((ks * 4 + cfa + rg) << 9));
    }

    float zacc[2][4];
#pragma unroll
    for (int rg = 0; rg < 2; ++rg)
#pragma unroll
        for (int r = 0; r < 4; ++r) zacc[rg][r] = 0.f;

    const bool bd  = (cs == (t >> 1));             // block's col-slice hits diagonal
    const int  jtd = (t & 1) * 2 + (wave >> 1);    // jt tile holding our diag rows

    for (int jt = 0; jt < 4; ++jt) {
        const char* gp = gp0 + (jt << 14);
        // stage 16 KB: 4 waves x 4 x 1KB DMA (linear; dest = uniform + lane*16)
#pragma unroll
        for (int i = 0; i < 4; ++i) {
            int c = wave * 4 + i;
            __builtin_amdgcn_global_load_lds(
                (gu32*)(gp + (c << 10) + (lane << 4)),
                (lu32*)(lds + (c << 10)), 16, 0, 0);
        }
        __syncthreads();

        const bool dgt = bd && (jt == jtd);        // this tile holds our diagonal
#pragma unroll
        for (int cf = 0; cf < 4; ++cf) {
            f32x4 acc[2];
            acc[0] = (f32x4){-KOFF, -KOFF, -KOFF, -KOFF};
            acc[1] = acc[0];
#pragma unroll
            for (int ks = 0; ks < 8; ++ks) {
                i64 b = *(const i64*)(lds + ((ks * 4 + cf) << 9) + lane * 8);
                acc[0] = __builtin_amdgcn_mfma_f32_16x16x32_fp8_fp8(
                    afrag[0][ks], b, acc[0], 0, 0, 0);
                acc[1] = __builtin_amdgcn_mfma_f32_16x16x32_fp8_fp8(
                    afrag[1][ks], b, acc[1], 0, 0, 0);
            }
            // C/D layout: col=lane&15, row=quad*4+reg (dtype-independent, m121+)
#pragma unroll
            for (int rg = 0; rg < 2; ++rg)
#pragma unroll
                for (int r = 0; r < 4; ++r)
                    zacc[rg][r] += __builtin_amdgcn_exp2f(acc[rg][r]);
            if (dgt) {                             // diag at cf == (wave&1)*2 + rg
#pragma unroll
                for (int rg = 0; rg < 2; ++rg)
                    if (cf == (wave & 1) * 2 + rg) {
#pragma unroll
                        for (int r = 0; r < 4; ++r)
                            if (quad * 4 + r == l15)
                                diag[rowbase + rg * 16 + l15] = acc[rg][r];
                    }
            }
        }
        __syncthreads();
    }

    // fold the 16 column-lane-classes (lanes differing in bits 0..3 share a row)
#pragma unroll
    for (int d = 1; d < 16; d <<= 1)
#pragma unroll
        for (int rg = 0; rg < 2; ++rg)
#pragma unroll
            for (int r = 0; r < 4; ++r)
                zacc[rg][r] += __shfl_xor(zacc[rg][r], d, 64);

    if (l15 == 0) {
#pragma unroll
        for (int rg = 0; rg < 2; ++rg)
#pragma unroll
            for (int r = 0; r < 4; ++r)
                zpart[(rowbase + rg * 16 + quad * 4 + r) * 32 + cs] = zacc[rg][r];
    }
}

// ---- kernel 2a: per-row loss, 32-block tree ----
__global__ __launch_bounds__(256) void k_fin1(const float* __restrict__ zpart,
                                              const float* __restrict__ diag,
                                              float* __restrict__ partial) {
    __shared__ float red[4];
    int r = blockIdx.x * 256 + threadIdx.x;
    const float4* z = (const float4*)(zpart + r * 32);
    float Z = 0.f;
#pragma unroll
    for (int i = 0; i < 8; ++i) {
        float4 a = z[i];
        Z += (a.x + a.y) + (a.z + a.w);
    }
    float p = __builtin_amdgcn_exp2f(diag[r]) / Z;  // diag already has -KOFF folded
    float v = -logf(p + 1e-5f);
#pragma unroll
    for (int dd = 1; dd < 64; dd <<= 1) v += __shfl_xor(v, dd, 64);
    if ((threadIdx.x & 63) == 0) red[threadIdx.x >> 6] = v;
    __syncthreads();
    if (threadIdx.x == 0)
        partial[blockIdx.x] = (red[0] + red[1]) + (red[2] + red[3]);
}

// ---- kernel 2b: final reduce ----
__global__ void k_fin2(const float* __restrict__ partial, float* __restrict__ out) {
    float v = (threadIdx.x < 32) ? partial[threadIdx.x] : 0.f;
#pragma unroll
    for (int d = 1; d < 32; d <<= 1) v += __shfl_xor(v, d, 64);
    if (threadIdx.x == 0) out[0] = v * (1.f / 8192.f);
}

extern "C" void kernel_launch(void* const* d_in, const int* in_sizes, int n_in,
                              void* d_out, int out_size, void* d_ws, size_t ws_size,
                              hipStream_t stream) {
    const float* q = (const float*)d_in[0];
    const float* g = (const float*)d_in[1];
    char* ws = (char*)d_ws;
    char*  qb     = ws;                                        // 2 MiB fp8 panels
    char*  gb     = ws + (2u << 20);                           // 2 MiB fp8 panels
    float* diag   = (float*)(ws + (4u << 20));                 // 32 KiB
    float* zpart  = (float*)(ws + (4u << 20) + (32u << 10));   // 1 MiB
    float* partial= (float*)(ws + (4u << 20) + (1056u << 10)); // 128 B
    k_cvt <<<2048, 256, 0, stream>>>(q, g, qb, gb);
    k_main<<<2048, 256, 0, stream>>>(qb, gb, zpart, diag);
    k_fin1<<<32,   256, 0, stream>>>(zpart, diag, partial);
    k_fin2<<<1,     64, 0, stream>>>(partial, (float*)d_out);
    (void)in_sizes; (void)n_in; (void)out_size; (void)ws_size;
}